// Round 12
// baseline (270.769 us; speedup 1.0000x reference)
//
#include <hip/hip_runtime.h>

#define N_NODES 8192
#define N_EDGES 262144
#define IN_CH 128
#define MP_CH 512
#define HID 256
#define KCL 10
#define EPS_C 0.001f
#define DELTA_C 0.311f
#define TV_COEFF_C 0.785f
#define BAL_COEFF_C 0.514f
#define RANK1 7373  // N - (N/K+1) + 1 : want smallest v with count(<=v) >= RANK1
#define DBINS 80    // degree histogram bins for load-balance sort

typedef __bf16 bf16x8 __attribute__((ext_vector_type(8)));
typedef float f32x4 __attribute__((ext_vector_type(4)));
typedef unsigned short ushort8 __attribute__((ext_vector_type(8)));

__device__ __forceinline__ float bf2f(unsigned short h) {
  union { unsigned int u; float f; } c; c.u = ((unsigned int)h) << 16; return c.f;
}
__device__ __forceinline__ unsigned short f2bf(float f) {
  union { float f; unsigned int u; } c; c.f = f;
  unsigned int r = c.u + 0x7fffu + ((c.u >> 16) & 1u);
  return (unsigned short)(r >> 16);
}

// ---------------- fused prep: bf16 converts + weight transposes + dst histogram -------------
__global__ void prep_kernel(const float* __restrict__ x, const float* __restrict__ W1,
                            const float* __restrict__ W2, const float* __restrict__ Wm1,
                            unsigned short* __restrict__ xb, unsigned short* __restrict__ W1bt,
                            unsigned short* __restrict__ W2bt, unsigned short* __restrict__ Wm1bt,
                            const int* __restrict__ dst, int* __restrict__ cnt) {
  int i = blockIdx.x * 256 + threadIdx.x;
  if (i < 1048576) { xb[i] = f2bf(x[i]); return; }
  i -= 1048576;
  if (i < 65536) { int n = i >> 7, k = i & 127; W1bt[i] = f2bf(W1[k * MP_CH + n]); return; }
  i -= 65536;
  if (i < 262144) { int n = i >> 9, k = i & 511; W2bt[i] = f2bf(W2[k * MP_CH + n]); return; }
  i -= 262144;
  if (i < 131072) { int n = i >> 9, k = i & 511; Wm1bt[i] = f2bf(Wm1[k * HID + n]); return; }
  i -= 131072;
  if (i < N_EDGES) atomicAdd(&cnt[dst[i]], 1);
}

// prefix-sum of per-node counts + degree-descending counting sort (for gtv load balance)
__global__ __launch_bounds__(1024) void scan_kernel(const int* __restrict__ cnt,
                                                    int* __restrict__ offs,
                                                    int* __restrict__ cursor,
                                                    int* __restrict__ nodeorder) {
  __shared__ int ts[1024];
  __shared__ int dh[DBINS];
  int t = threadIdx.x;
  int v[8]; int s = 0;
#pragma unroll
  for (int j = 0; j < 8; ++j) { v[j] = cnt[t * 8 + j]; s += v[j]; }
  if (t < DBINS) dh[t] = 0;
  ts[t] = s; __syncthreads();
  for (int off = 1; off < 1024; off <<= 1) {
    int add = (t >= off) ? ts[t - off] : 0;
    __syncthreads();
    ts[t] += add;
    __syncthreads();
  }
  int base = ts[t] - s;  // exclusive prefix
#pragma unroll
  for (int j = 0; j < 8; ++j) {
    offs[t * 8 + j] = base; cursor[t * 8 + j] = base; base += v[j];
    int key = v[j] < (DBINS - 1) ? v[j] : (DBINS - 1);
    atomicAdd(&dh[(DBINS - 1) - key], 1);  // descending-degree bins
  }
  if (t == 1023) offs[N_NODES] = ts[1023];
  __syncthreads();
  if (t == 0) {
    int acc0 = 0;
    for (int b = 0; b < DBINS; ++b) { int c = dh[b]; dh[b] = acc0; acc0 += c; }
  }
  __syncthreads();
#pragma unroll
  for (int j = 0; j < 8; ++j) {
    int key = v[j] < (DBINS - 1) ? v[j] : (DBINS - 1);
    int pos = atomicAdd(&dh[(DBINS - 1) - key], 1);
    nodeorder[pos] = t * 8 + j;
  }
}

// pack (src, weight) sorted by dst
__global__ void fill_kernel(const int* __restrict__ src, const int* __restrict__ dst,
                            const float* __restrict__ ew, int* __restrict__ cursor,
                            int2* __restrict__ esw) {
  for (int e = blockIdx.x * blockDim.x + threadIdx.x; e < N_EDGES; e += gridDim.x * blockDim.x) {
    int p = atomicAdd(&cursor[dst[e]], 1);
    esw[p] = make_int2(src[e], __float_as_int(ew[e]));
  }
}

// ---------------- n_edges = count of distinct (src,dst) pairs, via bucket dedup -------------
// esw is bucketed by dst: distinct pairs = per-bucket distinct srcs. One wave per node;
// lane at position p scans the bucket prefix [e0,p) for a matching src (L2-hot, ~deg^2/2
// reads per node ~= 500). Replaces: 8 MB bitmap memset + 262K atomicOr + 8 MB popcount pass.
// (edge weights are uniform(0,1): adj cell sums are nonzero with probability 1, so
// count_nonzero(adj) == distinct-pair count, matching the reference bitmap semantics.)
__global__ __launch_bounds__(256) void dedup_kernel(const int2* __restrict__ esw,
                                                    const int* __restrict__ offs,
                                                    float* __restrict__ scal) {
  __shared__ int wsum[4];
  int lane = threadIdx.x & 63;
  int wv = threadIdx.x >> 6;
  int d = blockIdx.x * 4 + wv;
  int e0 = offs[d], e1 = offs[d + 1];
  int cnt = 0;
  for (int p = e0 + lane; p < e1; p += 64) {
    int sp = esw[p].x;
    bool dup = false;
    for (int q = e0; q < p; ++q) dup |= (esw[q].x == sp);
    cnt += dup ? 0 : 1;
  }
#pragma unroll
  for (int m = 1; m < 64; m <<= 1) cnt += __shfl_xor(cnt, m, 64);
  if (lane == 0) wsum[wv] = cnt;
  __syncthreads();
  if (threadIdx.x == 0)
    atomicAdd((int*)(scal + 2), wsum[0] + wsum[1] + wsum[2] + wsum[3]);
}

// ---------------- MFMA GEMM: C[M,N] = A[M,K] @ BT[N,K]^T  (bf16 in, f32 acc) ----------------
// epi==1: C f32 = relu(v + bias)   (layer 3; dword stores are 64B-coalesced already)
// epi==2: Cb bf16 = v via LDS re-tile epilogue (coalesced 16B stores; bit-exact same values)
__global__ __launch_bounds__(256) void gemm_bt(
    const unsigned short* __restrict__ A, const unsigned short* __restrict__ BT,
    float* __restrict__ C, unsigned short* __restrict__ Cb,
    const float* __restrict__ bias, int N, int K, int epi) {
  __shared__ unsigned short lsm[2 * 128 * 32];  // lA | lB ; reused as f32 buf in epilogue
  unsigned short* lA = lsm;
  unsigned short* lB = lsm + 128 * 32;
  int lane = threadIdx.x & 63;
  int wv = threadIdx.x >> 6;
  int tm = blockIdx.y * 128, tn = blockIdx.x * 128;
  int wm = (wv >> 1) * 64, wn = (wv & 1) * 64;
  int rA = lane & 15, quad = lane >> 4;
  f32x4 acc[4][4];
#pragma unroll
  for (int i = 0; i < 4; ++i)
#pragma unroll
    for (int j = 0; j < 4; ++j) acc[i][j] = (f32x4){0.f, 0.f, 0.f, 0.f};

  int arow = wv * 32 + (lane >> 2);
  int acol = (lane & 3) * 8;

  for (int k0 = 0; k0 < K; k0 += 32) {
#pragma unroll
    for (int c = 0; c < 2; ++c) {
      const unsigned short* ga = A + (size_t)(tm + arow + c * 16) * K + k0 + acol;
      __builtin_amdgcn_global_load_lds(
          (const __attribute__((address_space(1))) unsigned int*)ga,
          (__attribute__((address_space(3))) unsigned int*)(lA + (wv * 32 + c * 16) * 32),
          16, 0, 0);
      const unsigned short* gb = BT + (size_t)(tn + arow + c * 16) * K + k0 + acol;
      __builtin_amdgcn_global_load_lds(
          (const __attribute__((address_space(1))) unsigned int*)gb,
          (__attribute__((address_space(3))) unsigned int*)(lB + (wv * 32 + c * 16) * 32),
          16, 0, 0);
    }
    __syncthreads();
    bf16x8 af[4], bfr[4];
#pragma unroll
    for (int i = 0; i < 4; ++i)
      af[i] = *(const bf16x8*)(lA + (wm + i * 16 + rA) * 32 + quad * 8);
#pragma unroll
    for (int j = 0; j < 4; ++j)
      bfr[j] = *(const bf16x8*)(lB + (wn + j * 16 + rA) * 32 + quad * 8);
#pragma unroll
    for (int i = 0; i < 4; ++i)
#pragma unroll
      for (int j = 0; j < 4; ++j)
        acc[i][j] = __builtin_amdgcn_mfma_f32_16x16x32_bf16(af[i], bfr[j], acc[i][j], 0, 0, 0);
    __syncthreads();
  }

  if (epi == 1) {
#pragma unroll
    for (int i = 0; i < 4; ++i)
#pragma unroll
      for (int j = 0; j < 4; ++j)
#pragma unroll
        for (int r = 0; r < 4; ++r) {
          int row = tm + wm + i * 16 + quad * 4 + r;
          int col = tn + wn + j * 16 + rA;
          float v = acc[i][j][r] + bias[col];
          C[(size_t)row * N + col] = fmaxf(v, 0.f);
        }
  } else {
    float* fbuf = (float*)lsm;
    int band = threadIdx.x >> 7;
    int rrow = (threadIdx.x >> 3) & 15;
    int cg = threadIdx.x & 7;
#pragma unroll
    for (int i = 0; i < 4; ++i) {
#pragma unroll
      for (int j = 0; j < 4; ++j)
#pragma unroll
        for (int r = 0; r < 4; ++r)
          fbuf[(wv >> 1) * (16 * 128) + (quad * 4 + r) * 128 + (wn + j * 16 + rA)] =
              acc[i][j][r];
      __syncthreads();
      const float* sr = fbuf + band * (16 * 128) + rrow * 128 + cg * 16;
      unsigned short ov[16];
#pragma unroll
      for (int c = 0; c < 16; ++c) ov[c] = f2bf(sr[c]);
      size_t base = (size_t)(tm + band * 64 + i * 16 + rrow) * N + tn + cg * 16;
      *(ushort8*)(Cb + base) = *(ushort8*)ov;
      *(ushort8*)(Cb + base + 8) = *(ushort8*)(ov + 8);
      __syncthreads();
    }
  }
}

// ---------------- fused GTV node pass: TWO waves per node (half edge list each) -------------
// Inner loop is locally optimal (R3 4-edge ILP spills, R5 prefetch regresses, R7 fp8 neutral,
// R10 packed-f16 regresses). acc = sum_e gamma*(h_d - h_s): self-loops cancel exactly.
__global__ __launch_bounds__(256, 8) void gtv_node(
    const unsigned short* __restrict__ hb, const float* __restrict__ bias,
    const int2* __restrict__ esw, const int* __restrict__ offs,
    const int* __restrict__ nodeorder, unsigned short* __restrict__ outb) {
  __shared__ float sacc[2][MP_CH];
  int lane = threadIdx.x & 63;
  int wv = threadIdx.x >> 6;
  int pair = wv >> 1;          // 0,1 : node slot within block
  int half = wv & 1;           // 0,1 : which half of the edge list
  int d = __builtin_amdgcn_readfirstlane(nodeorder[blockIdx.x * 2 + pair]);
  ushort8 hdv = ((const ushort8*)(hb + (size_t)d * MP_CH))[lane];
  float hd[8], acc[8];
#pragma unroll
  for (int j = 0; j < 8; ++j) { hd[j] = bf2f(hdv[j]); acc[j] = 0.f; }
  int n0 = offs[d], n1 = offs[d + 1];
  int mid = n0 + ((n1 - n0 + 1) >> 1);
  int e0 = half ? mid : n0;
  int e1 = half ? n1 : mid;
  int i = e0;
  for (; i + 1 < e1; i += 2) {
    int2 ma = esw[i], mb = esw[i + 1];
    float wa = __int_as_float(ma.y), wb = __int_as_float(mb.y);
    ushort8 va = ((const ushort8*)(hb + (size_t)ma.x * MP_CH))[lane];
    ushort8 vb = ((const ushort8*)(hb + (size_t)mb.x * MP_CH))[lane];
    float pa = 0.f, pb = 0.f;
#pragma unroll
    for (int j = 0; j < 8; ++j) {
      pa += fabsf(hd[j] - bf2f(va[j]));
      pb += fabsf(hd[j] - bf2f(vb[j]));
    }
#pragma unroll
    for (int m = 1; m < 64; m <<= 1) { pa += __shfl_xor(pa, m, 64); pb += __shfl_xor(pb, m, 64); }
    float ga = wa * __builtin_amdgcn_rcpf(fmaxf(pa, EPS_C));
    float gb = wb * __builtin_amdgcn_rcpf(fmaxf(pb, EPS_C));
#pragma unroll
    for (int j = 0; j < 8; ++j)
      acc[j] += ga * (hd[j] - bf2f(va[j])) + gb * (hd[j] - bf2f(vb[j]));
  }
  if (i < e1) {
    int2 m0 = esw[i];
    float w = __int_as_float(m0.y);
    ushort8 sv = ((const ushort8*)(hb + (size_t)m0.x * MP_CH))[lane];
    float part = 0.f;
#pragma unroll
    for (int j = 0; j < 8; ++j) part += fabsf(hd[j] - bf2f(sv[j]));
#pragma unroll
    for (int m = 1; m < 64; m <<= 1) part += __shfl_xor(part, m, 64);
    float g = w * __builtin_amdgcn_rcpf(fmaxf(part, EPS_C));
#pragma unroll
    for (int j = 0; j < 8; ++j) acc[j] += g * (hd[j] - bf2f(sv[j]));
  }
  // combine halves: half1 publishes, half0 merges + does the epilogue
  if (half) {
#pragma unroll
    for (int j = 0; j < 8; ++j) sacc[pair][lane * 8 + j] = acc[j];
  }
  __syncthreads();
  if (!half) {
    const f32x4* br = (const f32x4*)(bias + lane * 8);
    f32x4 b0 = br[0], b1 = br[1];
    unsigned short ov[8];
#pragma unroll
    for (int j = 0; j < 8; ++j) {
      float tot = acc[j] + sacc[pair][lane * 8 + j];
      float bv = (j < 4) ? b0[j] : b1[j - 4];
      float o = hd[j] - DELTA_C * tot + bv;
      o = (o > 0.f) ? o : (expf(o) - 1.f);
      ov[j] = f2bf(o);
    }
    *((ushort8*)(outb + (size_t)d * MP_CH) + lane) = *(ushort8*)ov;
  }
}

// ---------------- head GEMM + fused softmax: wave per row --------------------
__global__ __launch_bounds__(256) void gemm_small(
    const float* __restrict__ hm, const float* __restrict__ W,
    const float* __restrict__ b, float* __restrict__ out, float* __restrict__ s) {
  __shared__ float lw[HID * KCL];
  __shared__ float lb[KCL];
  for (int i = threadIdx.x; i < HID * KCL; i += 256) lw[i] = W[i];
  if (threadIdx.x < KCL) lb[threadIdx.x] = b[threadIdx.x];
  __syncthreads();
  int lane = threadIdx.x & 63, wv = threadIdx.x >> 6;
  int row = blockIdx.x * 4 + wv;
  f32x4 hv = *(const f32x4*)(hm + (size_t)row * HID + lane * 4);
  float p[KCL];
#pragma unroll
  for (int n = 0; n < KCL; ++n) {
    int k0 = lane * 4;
    p[n] = hv[0] * lw[(k0 + 0) * KCL + n] + hv[1] * lw[(k0 + 1) * KCL + n] +
           hv[2] * lw[(k0 + 2) * KCL + n] + hv[3] * lw[(k0 + 3) * KCL + n];
  }
#pragma unroll
  for (int n = 0; n < KCL; ++n)
#pragma unroll
    for (int m = 1; m < 64; m <<= 1) p[n] += __shfl_xor(p[n], m, 64);
  if (lane == 0) {
    float vv[KCL]; float mx = -1e30f;
#pragma unroll
    for (int n = 0; n < KCL; ++n) {
      vv[n] = p[n] + lb[n];
      out[(size_t)row * KCL + n] = vv[n];
      mx = fmaxf(mx, vv[n]);
    }
    float sum = 0.f;
#pragma unroll
    for (int n = 0; n < KCL; ++n) { vv[n] = expf(vv[n] - mx); sum += vv[n]; }
    float inv = 1.f / sum;
#pragma unroll
    for (int n = 0; n < KCL; ++n) s[(size_t)row * KCL + n] = vv[n] * inv;
  }
}

// ---------------- fused losses: TV (blocks 0..245) + quant/bal (246..255) + finalize --------
// scal: [0]=tv [1]=asym [2]=n_edges(int, from dedup_kernel) [3]=done-counter(int)
__global__ __launch_bounds__(1024) void tvquant_kernel(
    const int* __restrict__ src, const int* __restrict__ dst,
    const float* __restrict__ ew, const float* __restrict__ s,
    float* __restrict__ scal, float* __restrict__ out) {
  __shared__ float fsh[16];
  __shared__ int wcnt[2][16];
  int t = threadIdx.x;
  int lane = t & 63, wv = t >> 6;
  if (blockIdx.x < 246) {
    float local = 0.f;
    for (int e = blockIdx.x * 1024 + t; e < N_EDGES; e += 246 * 1024) {
      int a = src[e], b = dst[e];
      float w = ew[e];
      const float* sa = s + (size_t)a * KCL;
      const float* sb = s + (size_t)b * KCL;
      float tv = 0.f;
#pragma unroll
      for (int k = 0; k < KCL; ++k) tv += fabsf(sa[k] - sb[k]);
      local += w * tv;
    }
#pragma unroll
    for (int m = 1; m < 64; m <<= 1) local += __shfl_xor(local, m, 64);
    if (lane == 0) fsh[wv] = local;
    __syncthreads();
    if (t == 0) {
      float tot = 0.f;
#pragma unroll
      for (int i2 = 0; i2 < 16; ++i2) tot += fsh[i2];
      atomicAdd(&scal[0], tot);
    }
  } else {
    int k = blockIdx.x - 246;
    unsigned int v[8];
#pragma unroll
    for (int j = 0; j < 8; ++j)
      v[j] = __float_as_uint(s[(size_t)(t + j * 1024) * KCL + k]);
    unsigned int lo = 0u, hi = 0x3F800000u;  // softmax in (0, 1]
    int p = 0;
    while (lo < hi) {
      unsigned int mid = (lo + hi) >> 1;
      int c = 0;
#pragma unroll
      for (int j = 0; j < 8; ++j) c += (v[j] <= mid) ? 1 : 0;
#pragma unroll
      for (int m = 1; m < 64; m <<= 1) c += __shfl_xor(c, m, 64);
      if (lane == 0) wcnt[p][wv] = c;
      __syncthreads();
      int tot = 0;
#pragma unroll
      for (int i2 = 0; i2 < 16; ++i2) tot += wcnt[p][i2];
      if (tot >= RANK1) hi = mid; else lo = mid + 1;
      p ^= 1;
    }
    float q = __uint_as_float(lo);
    float local = 0.f;
#pragma unroll
    for (int j = 0; j < 8; ++j) {
      float tt = __uint_as_float(v[j]) - q;
      local += (tt >= 0.f) ? 9.f * tt : -tt;
    }
#pragma unroll
    for (int m = 1; m < 64; m <<= 1) local += __shfl_xor(local, m, 64);
    if (lane == 0) fsh[wv] = local;
    __syncthreads();
    if (t == 0) {
      float tot = 0.f;
#pragma unroll
      for (int i2 = 0; i2 < 16; ++i2) tot += fsh[i2];
      atomicAdd(&scal[1], tot);
    }
  }
  // last-finished block finalizes (n_edges from dedup_kernel is stream-ordered visible)
  if (t == 0) {
    __threadfence();
    int dn = atomicAdd((int*)(scal + 3), 1);
    if (dn == 255) {
      float tv = scal[0], asym = scal[1];
      float nedges = (float)(*(int*)(scal + 2));
      out[N_NODES * KCL] = TV_COEFF_C * (tv / (2.f * nedges));
      out[N_NODES * KCL + 1] = BAL_COEFF_C * ((73728.f - asym) / 73728.f);
    }
  }
}

// ---------------- workspace layout (bytes) ----------------
// [0, 33024) is zeroed by ONE small memset per launch: cnt + scal (no more 8 MB bitmap)
#define OFF_CNT    ((size_t)0)            // 32 KB histogram
#define OFF_SCAL   ((size_t)32768)        // 256 B scalars
#define OFF_OFFS   ((size_t)33280)        // 32 KB + 4
#define OFF_CURSOR ((size_t)66560)        // 32 KB
#define OFF_NORD   ((size_t)99328)        // 32 KB degree-sorted node order
#define OFF_HB     ((size_t)16777216)     // 8 MB bf16 h
#define OFF_OUTB   ((size_t)25165824)     // 8 MB bf16 elu output
#define OFF_HM     ((size_t)33554432)     // 8 MB f32 hm; esw (2 MB int2) aliases the front
#define OFF_XB     ((size_t)41943040)     // 2 MB bf16 x
#define OFF_W1BT   ((size_t)44040192)
#define OFF_W2BT   ((size_t)44171264)
#define OFF_WM1BT  ((size_t)44695552)
#define OFF_S      ((size_t)44957696)     // softmax s

extern "C" void kernel_launch(void* const* d_in, const int* in_sizes, int n_in,
                              void* d_out, int out_size, void* d_ws, size_t ws_size,
                              hipStream_t stream) {
  const float* x   = (const float*)d_in[0];
  const int*   ei  = (const int*)d_in[1];
  const float* ew  = (const float*)d_in[2];
  const float* W1  = (const float*)d_in[3];
  const float* b1  = (const float*)d_in[4];
  const float* W2  = (const float*)d_in[5];
  const float* b2  = (const float*)d_in[6];
  const float* Wm1 = (const float*)d_in[7];
  const float* bm1 = (const float*)d_in[8];
  const float* Wm2 = (const float*)d_in[9];
  const float* bm2 = (const float*)d_in[10];
  float* out = (float*)d_out;

  char* ws = (char*)d_ws;
  int*            cnt    = (int*)(ws + OFF_CNT);
  float*          scal   = (float*)(ws + OFF_SCAL);
  int*            offs   = (int*)(ws + OFF_OFFS);
  int*            cursor = (int*)(ws + OFF_CURSOR);
  int*            nord   = (int*)(ws + OFF_NORD);
  unsigned short* hb     = (unsigned short*)(ws + OFF_HB);
  unsigned short* outb   = (unsigned short*)(ws + OFF_OUTB);
  float*          hm     = (float*)(ws + OFF_HM);
  int2*           esw    = (int2*)(ws + OFF_HM);  // alias: dead before gemm3 writes hm
  unsigned short* xb     = (unsigned short*)(ws + OFF_XB);
  unsigned short* W1bt   = (unsigned short*)(ws + OFF_W1BT);
  unsigned short* W2bt   = (unsigned short*)(ws + OFF_W2BT);
  unsigned short* Wm1bt  = (unsigned short*)(ws + OFF_WM1BT);
  float*          s      = (float*)(ws + OFF_S);

  const int* srcA = ei;
  const int* dstA = ei + N_EDGES;

  // one small memset covers cnt + scal (contiguous; bitmap is gone)
  hipMemsetAsync(ws, 0, 33024, stream);

  prep_kernel<<<6912, 256, 0, stream>>>(x, W1, W2, Wm1, xb, W1bt, W2bt, Wm1bt, dstA, cnt);
  scan_kernel<<<1, 1024, 0, stream>>>(cnt, offs, cursor, nord);
  fill_kernel<<<1024, 256, 0, stream>>>(srcA, dstA, ew, cursor, esw);
  dedup_kernel<<<N_NODES / 4, 256, 0, stream>>>(esw, offs, scal);  // n_edges, overlaps nothing hot

  // layer 1
  gemm_bt<<<dim3(MP_CH / 128, N_NODES / 128), 256, 0, stream>>>(
      xb, W1bt, nullptr, hb, nullptr, MP_CH, IN_CH, 2);
  gtv_node<<<N_NODES / 2, 256, 0, stream>>>(hb, b1, esw, offs, nord, outb);
  // layer 2
  gemm_bt<<<dim3(MP_CH / 128, N_NODES / 128), 256, 0, stream>>>(
      outb, W2bt, nullptr, hb, nullptr, MP_CH, MP_CH, 2);
  gtv_node<<<N_NODES / 2, 256, 0, stream>>>(hb, b2, esw, offs, nord, outb);
  // MLP head (gemm3 overwrites the esw alias region -- esw is dead now)
  gemm_bt<<<dim3(HID / 128, N_NODES / 128), 256, 0, stream>>>(
      outb, Wm1bt, hm, nullptr, bm1, HID, MP_CH, 1);
  gemm_small<<<N_NODES / 4, 256, 0, stream>>>(hm, Wm2, bm2, out, s);

  // losses: tv + quant/bal + finalize in ONE kernel (n_edges already computed by dedup)
  tvquant_kernel<<<256, 1024, 0, stream>>>(srcA, dstA, ew, s, scal, out);
}

// Round 13
// 259.004 us; speedup vs baseline: 1.0454x; 1.0454x over previous
//
#include <hip/hip_runtime.h>

#define N_NODES 8192
#define N_EDGES 262144
#define IN_CH 128
#define MP_CH 512
#define HID 256
#define KCL 10
#define EPS_C 0.001f
#define DELTA_C 0.311f
#define TV_COEFF_C 0.785f
#define BAL_COEFF_C 0.514f
#define RANK1 7373  // N - (N/K+1) + 1 : want smallest v with count(<=v) >= RANK1
#define DBINS 80    // degree histogram bins for load-balance sort

typedef __bf16 bf16x8 __attribute__((ext_vector_type(8)));
typedef float f32x4 __attribute__((ext_vector_type(4)));
typedef unsigned short ushort8 __attribute__((ext_vector_type(8)));

__device__ __forceinline__ float bf2f(unsigned short h) {
  union { unsigned int u; float f; } c; c.u = ((unsigned int)h) << 16; return c.f;
}
__device__ __forceinline__ unsigned short f2bf(float f) {
  union { float f; unsigned int u; } c; c.f = f;
  unsigned int r = c.u + 0x7fffu + ((c.u >> 16) & 1u);
  return (unsigned short)(r >> 16);
}

// ---------------- fused prep: bf16 converts + weight transposes + dst histogram -------------
__global__ void prep_kernel(const float* __restrict__ x, const float* __restrict__ W1,
                            const float* __restrict__ W2, const float* __restrict__ Wm1,
                            unsigned short* __restrict__ xb, unsigned short* __restrict__ W1bt,
                            unsigned short* __restrict__ W2bt, unsigned short* __restrict__ Wm1bt,
                            const int* __restrict__ dst, int* __restrict__ cnt) {
  int i = blockIdx.x * 256 + threadIdx.x;
  if (i < 1048576) { xb[i] = f2bf(x[i]); return; }
  i -= 1048576;
  if (i < 65536) { int n = i >> 7, k = i & 127; W1bt[i] = f2bf(W1[k * MP_CH + n]); return; }
  i -= 65536;
  if (i < 262144) { int n = i >> 9, k = i & 511; W2bt[i] = f2bf(W2[k * MP_CH + n]); return; }
  i -= 262144;
  if (i < 131072) { int n = i >> 9, k = i & 511; Wm1bt[i] = f2bf(Wm1[k * HID + n]); return; }
  i -= 131072;
  if (i < N_EDGES) atomicAdd(&cnt[dst[i]], 1);
}

// prefix-sum of per-node counts + degree-descending counting sort (for gtv load balance)
__global__ __launch_bounds__(1024) void scan_kernel(const int* __restrict__ cnt,
                                                    int* __restrict__ offs,
                                                    int* __restrict__ cursor,
                                                    int* __restrict__ nodeorder) {
  __shared__ int ts[1024];
  __shared__ int dh[DBINS];
  int t = threadIdx.x;
  int v[8]; int s = 0;
#pragma unroll
  for (int j = 0; j < 8; ++j) { v[j] = cnt[t * 8 + j]; s += v[j]; }
  if (t < DBINS) dh[t] = 0;
  ts[t] = s; __syncthreads();
  for (int off = 1; off < 1024; off <<= 1) {
    int add = (t >= off) ? ts[t - off] : 0;
    __syncthreads();
    ts[t] += add;
    __syncthreads();
  }
  int base = ts[t] - s;  // exclusive prefix
#pragma unroll
  for (int j = 0; j < 8; ++j) {
    offs[t * 8 + j] = base; cursor[t * 8 + j] = base; base += v[j];
    int key = v[j] < (DBINS - 1) ? v[j] : (DBINS - 1);
    atomicAdd(&dh[(DBINS - 1) - key], 1);  // descending-degree bins
  }
  if (t == 1023) offs[N_NODES] = ts[1023];
  __syncthreads();
  if (t == 0) {
    int acc0 = 0;
    for (int b = 0; b < DBINS; ++b) { int c = dh[b]; dh[b] = acc0; acc0 += c; }
  }
  __syncthreads();
#pragma unroll
  for (int j = 0; j < 8; ++j) {
    int key = v[j] < (DBINS - 1) ? v[j] : (DBINS - 1);
    int pos = atomicAdd(&dh[(DBINS - 1) - key], 1);
    nodeorder[pos] = t * 8 + j;
  }
}

// pack (src, weight) sorted by dst
__global__ void fill_kernel(const int* __restrict__ src, const int* __restrict__ dst,
                            const float* __restrict__ ew, int* __restrict__ cursor,
                            int2* __restrict__ esw) {
  for (int e = blockIdx.x * blockDim.x + threadIdx.x; e < N_EDGES; e += gridDim.x * blockDim.x) {
    int p = atomicAdd(&cursor[dst[e]], 1);
    esw[p] = make_int2(src[e], __float_as_int(ew[e]));
  }
}

// ---------------- MFMA GEMM: C[M,N] = A[M,K] @ BT[N,K]^T  (bf16 in, f32 acc) ----------------
// epi==1: C f32 = relu(v + bias)   (layer 3; dword stores are 64B-coalesced already)
// epi==2: Cb bf16 = v via LDS re-tile epilogue (coalesced 16B stores; bit-exact same values)
__global__ __launch_bounds__(256) void gemm_bt(
    const unsigned short* __restrict__ A, const unsigned short* __restrict__ BT,
    float* __restrict__ C, unsigned short* __restrict__ Cb,
    const float* __restrict__ bias, int N, int K, int epi) {
  __shared__ unsigned short lsm[2 * 128 * 32];  // lA | lB ; reused as f32 buf in epilogue
  unsigned short* lA = lsm;
  unsigned short* lB = lsm + 128 * 32;
  int lane = threadIdx.x & 63;
  int wv = threadIdx.x >> 6;
  int tm = blockIdx.y * 128, tn = blockIdx.x * 128;
  int wm = (wv >> 1) * 64, wn = (wv & 1) * 64;
  int rA = lane & 15, quad = lane >> 4;
  f32x4 acc[4][4];
#pragma unroll
  for (int i = 0; i < 4; ++i)
#pragma unroll
    for (int j = 0; j < 4; ++j) acc[i][j] = (f32x4){0.f, 0.f, 0.f, 0.f};

  int arow = wv * 32 + (lane >> 2);
  int acol = (lane & 3) * 8;

  for (int k0 = 0; k0 < K; k0 += 32) {
#pragma unroll
    for (int c = 0; c < 2; ++c) {
      const unsigned short* ga = A + (size_t)(tm + arow + c * 16) * K + k0 + acol;
      __builtin_amdgcn_global_load_lds(
          (const __attribute__((address_space(1))) unsigned int*)ga,
          (__attribute__((address_space(3))) unsigned int*)(lA + (wv * 32 + c * 16) * 32),
          16, 0, 0);
      const unsigned short* gb = BT + (size_t)(tn + arow + c * 16) * K + k0 + acol;
      __builtin_amdgcn_global_load_lds(
          (const __attribute__((address_space(1))) unsigned int*)gb,
          (__attribute__((address_space(3))) unsigned int*)(lB + (wv * 32 + c * 16) * 32),
          16, 0, 0);
    }
    __syncthreads();
    bf16x8 af[4], bfr[4];
#pragma unroll
    for (int i = 0; i < 4; ++i)
      af[i] = *(const bf16x8*)(lA + (wm + i * 16 + rA) * 32 + quad * 8);
#pragma unroll
    for (int j = 0; j < 4; ++j)
      bfr[j] = *(const bf16x8*)(lB + (wn + j * 16 + rA) * 32 + quad * 8);
#pragma unroll
    for (int i = 0; i < 4; ++i)
#pragma unroll
      for (int j = 0; j < 4; ++j)
        acc[i][j] = __builtin_amdgcn_mfma_f32_16x16x32_bf16(af[i], bfr[j], acc[i][j], 0, 0, 0);
    __syncthreads();
  }

  if (epi == 1) {
#pragma unroll
    for (int i = 0; i < 4; ++i)
#pragma unroll
      for (int j = 0; j < 4; ++j)
#pragma unroll
        for (int r = 0; r < 4; ++r) {
          int row = tm + wm + i * 16 + quad * 4 + r;
          int col = tn + wn + j * 16 + rA;
          float v = acc[i][j][r] + bias[col];
          C[(size_t)row * N + col] = fmaxf(v, 0.f);
        }
  } else {
    float* fbuf = (float*)lsm;
    int band = threadIdx.x >> 7;
    int rrow = (threadIdx.x >> 3) & 15;
    int cg = threadIdx.x & 7;
#pragma unroll
    for (int i = 0; i < 4; ++i) {
#pragma unroll
      for (int j = 0; j < 4; ++j)
#pragma unroll
        for (int r = 0; r < 4; ++r)
          fbuf[(wv >> 1) * (16 * 128) + (quad * 4 + r) * 128 + (wn + j * 16 + rA)] =
              acc[i][j][r];
      __syncthreads();
      const float* sr = fbuf + band * (16 * 128) + rrow * 128 + cg * 16;
      unsigned short ov[16];
#pragma unroll
      for (int c = 0; c < 16; ++c) ov[c] = f2bf(sr[c]);
      size_t base = (size_t)(tm + band * 64 + i * 16 + rrow) * N + tn + cg * 16;
      *(ushort8*)(Cb + base) = *(ushort8*)ov;
      *(ushort8*)(Cb + base + 8) = *(ushort8*)(ov + 8);
      __syncthreads();
    }
  }
}

// ---------------- fused GTV node pass: TWO waves per node (half edge list each) -------------
// Inner loop is locally optimal (R3 4-edge ILP spills, R5 prefetch regresses, R7 fp8 neutral,
// R10 packed-f16 regresses, R11 dedup regresses). acc = sum_e gamma*(h_d - h_s): self-loops
// cancel exactly despite bf16 gathers.
__global__ __launch_bounds__(256, 8) void gtv_node(
    const unsigned short* __restrict__ hb, const float* __restrict__ bias,
    const int2* __restrict__ esw, const int* __restrict__ offs,
    const int* __restrict__ nodeorder, unsigned short* __restrict__ outb) {
  __shared__ float sacc[2][MP_CH];
  int lane = threadIdx.x & 63;
  int wv = threadIdx.x >> 6;
  int pair = wv >> 1;          // 0,1 : node slot within block
  int half = wv & 1;           // 0,1 : which half of the edge list
  int d = __builtin_amdgcn_readfirstlane(nodeorder[blockIdx.x * 2 + pair]);
  ushort8 hdv = ((const ushort8*)(hb + (size_t)d * MP_CH))[lane];
  float hd[8], acc[8];
#pragma unroll
  for (int j = 0; j < 8; ++j) { hd[j] = bf2f(hdv[j]); acc[j] = 0.f; }
  int n0 = offs[d], n1 = offs[d + 1];
  int mid = n0 + ((n1 - n0 + 1) >> 1);
  int e0 = half ? mid : n0;
  int e1 = half ? n1 : mid;
  int i = e0;
  for (; i + 1 < e1; i += 2) {
    int2 ma = esw[i], mb = esw[i + 1];
    float wa = __int_as_float(ma.y), wb = __int_as_float(mb.y);
    ushort8 va = ((const ushort8*)(hb + (size_t)ma.x * MP_CH))[lane];
    ushort8 vb = ((const ushort8*)(hb + (size_t)mb.x * MP_CH))[lane];
    float pa = 0.f, pb = 0.f;
#pragma unroll
    for (int j = 0; j < 8; ++j) {
      pa += fabsf(hd[j] - bf2f(va[j]));
      pb += fabsf(hd[j] - bf2f(vb[j]));
    }
#pragma unroll
    for (int m = 1; m < 64; m <<= 1) { pa += __shfl_xor(pa, m, 64); pb += __shfl_xor(pb, m, 64); }
    float ga = wa * __builtin_amdgcn_rcpf(fmaxf(pa, EPS_C));
    float gb = wb * __builtin_amdgcn_rcpf(fmaxf(pb, EPS_C));
#pragma unroll
    for (int j = 0; j < 8; ++j)
      acc[j] += ga * (hd[j] - bf2f(va[j])) + gb * (hd[j] - bf2f(vb[j]));
  }
  if (i < e1) {
    int2 m0 = esw[i];
    float w = __int_as_float(m0.y);
    ushort8 sv = ((const ushort8*)(hb + (size_t)m0.x * MP_CH))[lane];
    float part = 0.f;
#pragma unroll
    for (int j = 0; j < 8; ++j) part += fabsf(hd[j] - bf2f(sv[j]));
#pragma unroll
    for (int m = 1; m < 64; m <<= 1) part += __shfl_xor(part, m, 64);
    float g = w * __builtin_amdgcn_rcpf(fmaxf(part, EPS_C));
#pragma unroll
    for (int j = 0; j < 8; ++j) acc[j] += g * (hd[j] - bf2f(sv[j]));
  }
  // combine halves: half1 publishes, half0 merges + does the epilogue
  if (half) {
#pragma unroll
    for (int j = 0; j < 8; ++j) sacc[pair][lane * 8 + j] = acc[j];
  }
  __syncthreads();
  if (!half) {
    const f32x4* br = (const f32x4*)(bias + lane * 8);
    f32x4 b0 = br[0], b1 = br[1];
    unsigned short ov[8];
#pragma unroll
    for (int j = 0; j < 8; ++j) {
      float tot = acc[j] + sacc[pair][lane * 8 + j];
      float bv = (j < 4) ? b0[j] : b1[j - 4];
      float o = hd[j] - DELTA_C * tot + bv;
      o = (o > 0.f) ? o : (expf(o) - 1.f);
      ov[j] = f2bf(o);
    }
    *((ushort8*)(outb + (size_t)d * MP_CH) + lane) = *(ushort8*)ov;
  }
}

// ---------------- head GEMM + fused softmax: wave per row --------------------
__global__ __launch_bounds__(256) void gemm_small(
    const float* __restrict__ hm, const float* __restrict__ W,
    const float* __restrict__ b, float* __restrict__ out, float* __restrict__ s) {
  __shared__ float lw[HID * KCL];
  __shared__ float lb[KCL];
  for (int i = threadIdx.x; i < HID * KCL; i += 256) lw[i] = W[i];
  if (threadIdx.x < KCL) lb[threadIdx.x] = b[threadIdx.x];
  __syncthreads();
  int lane = threadIdx.x & 63, wv = threadIdx.x >> 6;
  int row = blockIdx.x * 4 + wv;
  f32x4 hv = *(const f32x4*)(hm + (size_t)row * HID + lane * 4);
  float p[KCL];
#pragma unroll
  for (int n = 0; n < KCL; ++n) {
    int k0 = lane * 4;
    p[n] = hv[0] * lw[(k0 + 0) * KCL + n] + hv[1] * lw[(k0 + 1) * KCL + n] +
           hv[2] * lw[(k0 + 2) * KCL + n] + hv[3] * lw[(k0 + 3) * KCL + n];
  }
#pragma unroll
  for (int n = 0; n < KCL; ++n)
#pragma unroll
    for (int m = 1; m < 64; m <<= 1) p[n] += __shfl_xor(p[n], m, 64);
  if (lane == 0) {
    float vv[KCL]; float mx = -1e30f;
#pragma unroll
    for (int n = 0; n < KCL; ++n) {
      vv[n] = p[n] + lb[n];
      out[(size_t)row * KCL + n] = vv[n];
      mx = fmaxf(mx, vv[n]);
    }
    float sum = 0.f;
#pragma unroll
    for (int n = 0; n < KCL; ++n) { vv[n] = expf(vv[n] - mx); sum += vv[n]; }
    float inv = 1.f / sum;
#pragma unroll
    for (int n = 0; n < KCL; ++n) s[(size_t)row * KCL + n] = vv[n] * inv;
  }
}

// ---------------- fused losses A: TV (blocks 0..245) + quant/bal (blocks 246..255) ----------
__global__ __launch_bounds__(1024) void tvquant_kernel(
    const int* __restrict__ src, const int* __restrict__ dst,
    const float* __restrict__ ew, const float* __restrict__ s,
    unsigned int* __restrict__ bitmap, float* __restrict__ scal) {
  __shared__ float fsh[16];
  __shared__ int wcnt[2][16];
  int t = threadIdx.x;
  int lane = t & 63, wv = t >> 6;
  if (blockIdx.x < 246) {
    float local = 0.f;
    for (int e = blockIdx.x * 1024 + t; e < N_EDGES; e += 246 * 1024) {
      int a = src[e], b = dst[e];
      float w = ew[e];
      const float* sa = s + (size_t)a * KCL;
      const float* sb = s + (size_t)b * KCL;
      float tv = 0.f;
#pragma unroll
      for (int k = 0; k < KCL; ++k) tv += fabsf(sa[k] - sb[k]);
      local += w * tv;
      if (w != 0.f) {
        unsigned int key = ((unsigned int)a << 13) | (unsigned int)b;
        atomicOr(&bitmap[key >> 5], 1u << (key & 31u));
      }
    }
#pragma unroll
    for (int m = 1; m < 64; m <<= 1) local += __shfl_xor(local, m, 64);
    if (lane == 0) fsh[wv] = local;
    __syncthreads();
    if (t == 0) {
      float tot = 0.f;
#pragma unroll
      for (int i2 = 0; i2 < 16; ++i2) tot += fsh[i2];
      atomicAdd(&scal[0], tot);
    }
  } else {
    int k = blockIdx.x - 246;
    unsigned int v[8];
#pragma unroll
    for (int j = 0; j < 8; ++j)
      v[j] = __float_as_uint(s[(size_t)(t + j * 1024) * KCL + k]);
    unsigned int lo = 0u, hi = 0x3F800000u;  // softmax in (0, 1]
    int p = 0;
    while (lo < hi) {
      unsigned int mid = (lo + hi) >> 1;
      int c = 0;
#pragma unroll
      for (int j = 0; j < 8; ++j) c += (v[j] <= mid) ? 1 : 0;
#pragma unroll
      for (int m = 1; m < 64; m <<= 1) c += __shfl_xor(c, m, 64);
      if (lane == 0) wcnt[p][wv] = c;
      __syncthreads();
      int tot = 0;
#pragma unroll
      for (int i2 = 0; i2 < 16; ++i2) tot += wcnt[p][i2];
      if (tot >= RANK1) hi = mid; else lo = mid + 1;
      p ^= 1;
    }
    float q = __uint_as_float(lo);
    float local = 0.f;
#pragma unroll
    for (int j = 0; j < 8; ++j) {
      float tt = __uint_as_float(v[j]) - q;
      local += (tt >= 0.f) ? 9.f * tt : -tt;
    }
#pragma unroll
    for (int m = 1; m < 64; m <<= 1) local += __shfl_xor(local, m, 64);
    if (lane == 0) fsh[wv] = local;
    __syncthreads();
    if (t == 0) {
      float tot = 0.f;
#pragma unroll
      for (int i2 = 0; i2 < 16; ++i2) tot += fsh[i2];
      atomicAdd(&scal[1], tot);
    }
  }
}

// ---------------- fused losses B: popcount n_edges + last-block finalize ---------------------
__global__ __launch_bounds__(1024) void popcfin_kernel(const unsigned int* __restrict__ bm,
                                                       float* __restrict__ scal,
                                                       float* __restrict__ out) {
  __shared__ int ish[16];
  int t = threadIdx.x;
  int lane = t & 63, wv = t >> 6;
  int local = 0;
  for (int i = blockIdx.x * 1024 + t; i < (1 << 21); i += 256 * 1024)
    local += __popc(bm[i]);
#pragma unroll
  for (int m = 1; m < 64; m <<= 1) local += __shfl_xor(local, m, 64);
  if (lane == 0) ish[wv] = local;
  __syncthreads();
  if (t == 0) {
    int tot = 0;
#pragma unroll
    for (int i2 = 0; i2 < 16; ++i2) tot += ish[i2];
    atomicAdd((int*)(scal + 2), tot);
    __threadfence();
    int d = atomicAdd((int*)(scal + 3), 1);
    if (d == 255) {
      float tv = scal[0], asym = scal[1];
      float nedges = (float)(*(int*)(scal + 2));
      out[N_NODES * KCL] = TV_COEFF_C * (tv / (2.f * nedges));
      out[N_NODES * KCL + 1] = BAL_COEFF_C * ((73728.f - asym) / 73728.f);
    }
  }
}

// ---------------- workspace layout (bytes) ----------------
// [0, 8421632) is zeroed by ONE memset per launch: bitmap + cnt + scal
#define OFF_BM     ((size_t)0)            // 8 MB n_edges bitmap
#define OFF_CNT    ((size_t)8388608)      // 32 KB histogram
#define OFF_SCAL   ((size_t)8421376)      // 256 B scalars
#define OFF_OFFS   ((size_t)8421888)      // 32 KB + 4
#define OFF_CURSOR ((size_t)8454912)      // 32 KB
#define OFF_NORD   ((size_t)8487936)      // 32 KB degree-sorted node order
#define OFF_HB     ((size_t)16777216)     // 8 MB bf16 h
#define OFF_OUTB   ((size_t)25165824)     // 8 MB bf16 elu output
#define OFF_HM     ((size_t)33554432)     // 8 MB f32 hm; esw (2 MB int2) aliases the front
#define OFF_XB     ((size_t)41943040)     // 2 MB bf16 x
#define OFF_W1BT   ((size_t)44040192)
#define OFF_W2BT   ((size_t)44171264)
#define OFF_WM1BT  ((size_t)44695552)
#define OFF_S      ((size_t)44957696)     // softmax s

extern "C" void kernel_launch(void* const* d_in, const int* in_sizes, int n_in,
                              void* d_out, int out_size, void* d_ws, size_t ws_size,
                              hipStream_t stream) {
  const float* x   = (const float*)d_in[0];
  const int*   ei  = (const int*)d_in[1];
  const float* ew  = (const float*)d_in[2];
  const float* W1  = (const float*)d_in[3];
  const float* b1  = (const float*)d_in[4];
  const float* W2  = (const float*)d_in[5];
  const float* b2  = (const float*)d_in[6];
  const float* Wm1 = (const float*)d_in[7];
  const float* bm1 = (const float*)d_in[8];
  const float* Wm2 = (const float*)d_in[9];
  const float* bm2 = (const float*)d_in[10];
  float* out = (float*)d_out;

  char* ws = (char*)d_ws;
  unsigned int*   bitmap = (unsigned int*)(ws + OFF_BM);
  int*            cnt    = (int*)(ws + OFF_CNT);
  float*          scal   = (float*)(ws + OFF_SCAL);
  int*            offs   = (int*)(ws + OFF_OFFS);
  int*            cursor = (int*)(ws + OFF_CURSOR);
  int*            nord   = (int*)(ws + OFF_NORD);
  unsigned short* hb     = (unsigned short*)(ws + OFF_HB);
  unsigned short* outb   = (unsigned short*)(ws + OFF_OUTB);
  float*          hm     = (float*)(ws + OFF_HM);
  int2*           esw    = (int2*)(ws + OFF_HM);  // alias: dead before gemm3 writes hm
  unsigned short* xb     = (unsigned short*)(ws + OFF_XB);
  unsigned short* W1bt   = (unsigned short*)(ws + OFF_W1BT);
  unsigned short* W2bt   = (unsigned short*)(ws + OFF_W2BT);
  unsigned short* Wm1bt  = (unsigned short*)(ws + OFF_WM1BT);
  float*          s      = (float*)(ws + OFF_S);

  const int* srcA = ei;
  const int* dstA = ei + N_EDGES;

  // one memset covers bitmap + cnt + scal (contiguous)
  hipMemsetAsync(ws, 0, 8421632, stream);

  prep_kernel<<<6912, 256, 0, stream>>>(x, W1, W2, Wm1, xb, W1bt, W2bt, Wm1bt, dstA, cnt);
  scan_kernel<<<1, 1024, 0, stream>>>(cnt, offs, cursor, nord);
  fill_kernel<<<1024, 256, 0, stream>>>(srcA, dstA, ew, cursor, esw);

  // layer 1
  gemm_bt<<<dim3(MP_CH / 128, N_NODES / 128), 256, 0, stream>>>(
      xb, W1bt, nullptr, hb, nullptr, MP_CH, IN_CH, 2);
  gtv_node<<<N_NODES / 2, 256, 0, stream>>>(hb, b1, esw, offs, nord, outb);
  // layer 2
  gemm_bt<<<dim3(MP_CH / 128, N_NODES / 128), 256, 0, stream>>>(
      outb, W2bt, nullptr, hb, nullptr, MP_CH, MP_CH, 2);
  gtv_node<<<N_NODES / 2, 256, 0, stream>>>(hb, b2, esw, offs, nord, outb);
  // MLP head (gemm3 overwrites the esw alias region -- esw is dead now)
  gemm_bt<<<dim3(HID / 128, N_NODES / 128), 256, 0, stream>>>(
      outb, Wm1bt, hm, nullptr, bm1, HID, MP_CH, 1);
  gemm_small<<<N_NODES / 4, 256, 0, stream>>>(hm, Wm2, bm2, out, s);

  // losses: tv+quant fused, then popc+finalize fused
  tvquant_kernel<<<256, 1024, 0, stream>>>(srcA, dstA, ew, s, bitmap, scal);
  popcfin_kernel<<<256, 1024, 0, stream>>>(bitmap, scal, out);
}